// Round 16
// baseline (70.353 us; speedup 1.0000x reference)
//
#include <hip/hip_runtime.h>
#include <math.h>

#define LSEQ 512
#define EDIM 256
#define PDIM 2048
#define BP   64      // block p-tile
#define BK   32
#define NT   16      // K-steps = LSEQ/BK

typedef _Float16 f16x8 __attribute__((ext_vector_type(8)));
typedef _Float16 f16x4 __attribute__((ext_vector_type(4)));
typedef _Float16 f16x2 __attribute__((ext_vector_type(2)));
typedef float    f32x4 __attribute__((ext_vector_type(4)));

#if __has_builtin(__builtin_amdgcn_exp2f)
#define EXP2F(x) __builtin_amdgcn_exp2f(x)
#else
#define EXP2F(x) __expf((x) * 0.6931471805599453f)
#endif

__device__ inline f16x2 pk2(float a, float b) {
#if __has_builtin(__builtin_amdgcn_cvt_pkrtz)
    return __builtin_bit_cast(f16x2, __builtin_amdgcn_cvt_pkrtz(a, b));
#else
    f16x2 r; r[0] = (_Float16)a; r[1] = (_Float16)b; return r;
#endif
}

__device__ inline float hw_sin(float ang) {
#if __has_builtin(__builtin_amdgcn_sinf)
    float rev = ang * 0.15915494309189535f;
    return __builtin_amdgcn_sinf(rev - floorf(rev));
#else
    return sinf(ang);
#endif
}
__device__ inline float hw_cos(float ang) {
#if __has_builtin(__builtin_amdgcn_cosf)
    float rev = ang * 0.15915494309189535f;
    return __builtin_amdgcn_cosf(rev - floorf(rev));
#else
    return cosf(ang);
#endif
}

// Conflict-balanced interleaved tile layout (fp16 element offset) for a
// [rows][32] fp16 tile stored as 128B row-pairs. r = row, g = k-group (0..3).
__device__ __host__ inline int tile_off(int r, int g) {
    return ((r >> 1) << 6) + ((r & 1) << 5) + (((g ^ ((r >> 1) & 3)) & 3) << 3);
}

__device__ inline void g2lds16(const void* g, void* l) {
    __builtin_amdgcn_global_load_lds(
        (const __attribute__((address_space(1))) void*)g,
        (__attribute__((address_space(3))) void*)l, 16, 0, 0);
}

// ---- fused precompute: one block per (b, k-step) baset chunk ---------------
// Also writes params[b, l] = {-0.5/w^2 * log2e, log2(amp)} for its 32 l's.
__global__ __launch_bounds__(256) void precompute_all(
    const int*   __restrict__ bs,      // (B, L)
    const float* __restrict__ ls,      // (256, 3)
    const float* __restrict__ emb,     // (256, E)
    float2*      __restrict__ params,  // (B, L)
    _Float16*    __restrict__ baset) { // (B*NT) chunks of 16 KB
    const int b   = blockIdx.x >> 4;
    const int t   = blockIdx.x & 15;
    const int tid = threadIdx.x;       // = e (0..255)

    __shared__ int sByte[BK];
    if (tid < BK) {
        const int l    = t * BK + tid;
        const int byte = bs[b * LSEQ + l];
        sByte[tid] = byte;
        const float l1  = ls[byte * 3 + 1];
        const float l2  = ls[byte * 3 + 2];
        const float wdt = fabsf(l1) * 0.02f + 1e-5f;
        const float amp = 1.0f / (1.0f + __expf(-l2));
        params[b * LSEQ + l] = make_float2(-0.72134752f / (wdt * wdt),  // -0.5*log2e/w^2
                                           __log2f(amp));
    }
    __syncthreads();

    // PE dim e: pair index e>>1, phase e&1 (0=sin, 1=cos)
    const float div = __expf((float)(tid >> 1) * (-2.0f * 9.210340372f / 256.0f));
    _Float16* chunk = baset + ((size_t)blockIdx.x << 13);
#pragma unroll
    for (int g = 0; g < 4; ++g) {
        f16x8 v;
#pragma unroll
        for (int j = 0; j < 8; ++j) {
            const int lj  = g * 8 + j;
            const float ang = (float)(t * BK + lj) * div;
            const float pev = (tid & 1) ? hw_cos(ang) : hw_sin(ang);
            v[j] = (_Float16)(emb[sByte[lj] * EDIM + tid] + pev);
        }
        *(f16x8*)&chunk[tile_off(tid, g)] = v;
    }
}

// ----------------------------- MFMA field kernel ----------------------------
// Max-occupancy variant: block tile 64p x 128e (P split x32, E split x2).
// 512 thr (8 waves, 2x4), wave tile 32p x 32e, acc 2x2 f32x4 = 16 VGPR.
// LDS 28 KB; launch_bounds(512,8) -> target 4 blocks/CU = 32 waves/CU (cap).
__global__ __launch_bounds__(512, 8) void field_mfma(
    const float*    __restrict__ cpos,    // (B,P)
    const float2*   __restrict__ params,  // (B,L) {c2*log2e, log2(amp)}
    const _Float16* __restrict__ baset,   // pre-swizzled BASE^T chunks
    float*          __restrict__ out) {   // (B,P,E)

    __shared__ __align__(16) _Float16 sW[2][BP * BK];    // 2 x 4 KB
    __shared__ __align__(16) _Float16 sB[2][128 * BK];   // 2 x 8 KB (E half)
    __shared__ __align__(16) float2   sPrm[LSEQ];        // 4 KB

    const int orig = blockIdx.x;
    const int wg   = (orig & 7) * 512 + (orig >> 3);     // bijective XCD swizzle (4096%8==0)
    const int b    = wg >> 6;
    const int ptile= (wg >> 1) & 31;
    const int et   = wg & 1;

    const int tid = threadIdx.x, lane = tid & 63, wave = tid >> 6;
    const int c15 = lane & 15, g4 = lane >> 4;
    const int wrow = wave >> 2, wcol = wave & 3;         // 2 x 4 wave grid

    // W-gen role: thread -> (p row sp 0..63, k-subgroup sg 0..7 of 4 l's)
    const int sp = tid >> 3;
    const int sg = tid & 7;
    const float mypos = cpos[b * PDIM + ptile * BP + sp];
    const float invL  = 1.0f / (float)(LSEQ - 1);
    const int   woff  = tile_off(sp, sg >> 1) + (sg & 1) * 4;

    // frag read offsets: A rows wrow*32 + rt*16 + c15 (rt 0..1),
    //                    B rows wcol*32 + ct*16 + c15 (ct 0..1)
    int aoff[2], boff[2];
#pragma unroll
    for (int rt = 0; rt < 2; ++rt) aoff[rt] = tile_off(wrow * 32 + rt * 16 + c15, g4);
#pragma unroll
    for (int ct = 0; ct < 2; ++ct) boff[ct] = tile_off(wcol * 32 + ct * 16 + c15, g4);

    // ---- prologue: sPrm -> LDS; issue B0,B1 stage (1 load/thread/buffer) ----
    sPrm[tid] = params[b * LSEQ + tid];
    // chunk = 8192 elems per (b,t); et half = 4096 elems, contiguous
    const _Float16* bt = baset + ((size_t)b * NT << 13) + et * 4096;
#pragma unroll
    for (int buf = 0; buf < 2; ++buf) {
        const _Float16* src = bt + buf * 8192 + wave * 512 + lane * 8;
        g2lds16(src, &sB[buf][wave * 512]);
    }
    __syncthreads();

    // genW for K-step t into sW[dbuf]: 4 gaussians/thread, f16x4 write
    auto genW = [&](int t, int dbuf) {
        const float4* qp = (const float4*)&sPrm[t * BK + sg * 4];
        const float4 q01 = qp[0], q23 = qp[1];           // {c2,la}x4
        const float bl0 = (float)(t * BK + sg * 4) * invL;
        const float pd  = mypos - bl0;
        float w[4];
#define GW(i, c2, la) { float d = pd - (float)(i) * invL; \
                        w[i] = EXP2F(fmaf(d * d, (c2), (la))); }
        GW(0, q01.x, q01.y) GW(1, q01.z, q01.w)
        GW(2, q23.x, q23.y) GW(3, q23.z, q23.w)
#undef GW
        f16x4 wv;
        ((f16x2*)&wv)[0] = pk2(w[0], w[1]);
        ((f16x2*)&wv)[1] = pk2(w[2], w[3]);
        *(f16x4*)&sW[dbuf][woff] = wv;
    };

    genW(0, 0);
    __syncthreads();

    f32x4 acc[2][2];
#pragma unroll
    for (int i = 0; i < 2; ++i)
#pragma unroll
        for (int j = 0; j < 2; ++j) acc[i][j] = (f32x4)(0.f);

    // ---- main loop: one barrier per K-step (R6/R14 ordering) ----
    for (int t = 0; t < NT; ++t) {
        const int cur = t & 1;
        if (t < NT - 1) genW(t + 1, cur ^ 1);   // spare buffer, no hazard

        const _Float16* wb = sW[cur];
        const _Float16* bb = sB[cur];
        f16x8 af[2];
#pragma unroll
        for (int rt = 0; rt < 2; ++rt) af[rt] = *(const f16x8*)&wb[aoff[rt]];
        __builtin_amdgcn_s_setprio(1);
#pragma unroll
        for (int ct = 0; ct < 2; ++ct) {
            const f16x8 bf = *(const f16x8*)&bb[boff[ct]];
#pragma unroll
            for (int rt = 0; rt < 2; ++rt)
                acc[rt][ct] = __builtin_amdgcn_mfma_f32_16x16x32_f16(af[rt], bf, acc[rt][ct], 0, 0, 0);
        }
        __builtin_amdgcn_s_setprio(0);

        __syncthreads();   // drains W[t+1] ds_writes + B[t+1] stage gloads

        if (t < NT - 2) {  // issue B[t+2] into the buffer just freed
            const _Float16* src = bt + (t + 2) * 8192 + wave * 512 + lane * 8;
            g2lds16(src, &sB[cur][wave * 512]);
        }
    }

    // ---- epilogue: C/D 16x16 layout col=lane&15 (e), row=g4*4+reg (p) ----
#pragma unroll
    for (int rt = 0; rt < 2; ++rt)
#pragma unroll
        for (int ct = 0; ct < 2; ++ct) {
            const int e = et * 128 + wcol * 32 + ct * 16 + c15;
#pragma unroll
            for (int reg = 0; reg < 4; ++reg) {
                const int p = ptile * BP + wrow * 32 + rt * 16 + g4 * 4 + reg;
                out[((size_t)b * PDIM + p) * EDIM + e] = acc[rt][ct][reg];
            }
        }
}

extern "C" void kernel_launch(void* const* d_in, const int* in_sizes, int n_in,
                              void* d_out, int out_size, void* d_ws, size_t ws_size,
                              hipStream_t stream) {
    const int*   bs   = (const int*)d_in[0];
    const float* cpos = (const float*)d_in[1];
    const float* emb  = (const float*)d_in[2];
    const float* ls   = (const float*)d_in[3];

    const int B = in_sizes[0] / LSEQ;   // 64

    char* ws = (char*)d_ws;
    float2*   params = (float2*)ws;                   // 256 KB
    _Float16* baset  = (_Float16*)(ws + (1u << 18));  // 16 MB

    precompute_all<<<B * NT, 256, 0, stream>>>(bs, ls, emb, params, baset);
    const int nblocks = B * (PDIM / BP) * 2;          // 4096
    field_mfma<<<nblocks, 512, 0, stream>>>(cpos, params, baset, (float*)d_out);
}

// Round 17
// 64.086 us; speedup vs baseline: 1.0978x; 1.0978x over previous
//
#include <hip/hip_runtime.h>
#include <math.h>

#define LSEQ 512
#define EDIM 256
#define PDIM 2048
#define BM   128
#define BK   32
#define NT   16      // K-steps = LSEQ/BK

typedef _Float16 f16x8 __attribute__((ext_vector_type(8)));
typedef _Float16 f16x2 __attribute__((ext_vector_type(2)));
typedef float    f32x4 __attribute__((ext_vector_type(4)));

#if __has_builtin(__builtin_amdgcn_exp2f)
#define EXP2F(x) __builtin_amdgcn_exp2f(x)
#else
#define EXP2F(x) __expf((x) * 0.6931471805599453f)
#endif

__device__ inline f16x2 pk2(float a, float b) {
#if __has_builtin(__builtin_amdgcn_cvt_pkrtz)
    return __builtin_bit_cast(f16x2, __builtin_amdgcn_cvt_pkrtz(a, b));
#else
    f16x2 r; r[0] = (_Float16)a; r[1] = (_Float16)b; return r;
#endif
}

__device__ inline float hw_sin(float ang) {
#if __has_builtin(__builtin_amdgcn_sinf)
    float rev = ang * 0.15915494309189535f;
    return __builtin_amdgcn_sinf(rev - floorf(rev));
#else
    return sinf(ang);
#endif
}
__device__ inline float hw_cos(float ang) {
#if __has_builtin(__builtin_amdgcn_cosf)
    float rev = ang * 0.15915494309189535f;
    return __builtin_amdgcn_cosf(rev - floorf(rev));
#else
    return cosf(ang);
#endif
}

// Conflict-balanced interleaved tile layout (fp16 element offset) for a
// [rows][32] fp16 tile stored as 128B row-pairs. r = row, g = k-group (0..3).
__device__ __host__ inline int tile_off(int r, int g) {
    return ((r >> 1) << 6) + ((r & 1) << 5) + (((g ^ ((r >> 1) & 3)) & 3) << 3);
}

__device__ inline void g2lds16(const void* g, void* l) {
    __builtin_amdgcn_global_load_lds(
        (const __attribute__((address_space(1))) void*)g,
        (__attribute__((address_space(3))) void*)l, 16, 0, 0);
}

// ---- fused precompute: one block per (b, k-step) baset chunk ---------------
// Also writes params[b, l] = {-0.5/w^2 * log2e, log2(amp)} for its 32 l's.
__global__ __launch_bounds__(256) void precompute_all(
    const int*   __restrict__ bs,      // (B, L)
    const float* __restrict__ ls,      // (256, 3)
    const float* __restrict__ emb,     // (256, E)
    float2*      __restrict__ params,  // (B, L)
    _Float16*    __restrict__ baset) { // (B*NT) chunks of 16 KB
    const int b   = blockIdx.x >> 4;
    const int t   = blockIdx.x & 15;
    const int tid = threadIdx.x;       // = e (0..255)

    __shared__ int sByte[BK];
    if (tid < BK) {
        const int l    = t * BK + tid;
        const int byte = bs[b * LSEQ + l];
        sByte[tid] = byte;
        const float l1  = ls[byte * 3 + 1];
        const float l2  = ls[byte * 3 + 2];
        const float wdt = fabsf(l1) * 0.02f + 1e-5f;
        const float amp = 1.0f / (1.0f + __expf(-l2));
        params[b * LSEQ + l] = make_float2(-0.72134752f / (wdt * wdt),  // -0.5*log2e/w^2
                                           __log2f(amp));
    }
    __syncthreads();

    // PE dim e: pair index e>>1, phase e&1 (0=sin, 1=cos)
    const float div = __expf((float)(tid >> 1) * (-2.0f * 9.210340372f / 256.0f));
    _Float16* chunk = baset + ((size_t)blockIdx.x << 13);
#pragma unroll
    for (int g = 0; g < 4; ++g) {
        f16x8 v;
#pragma unroll
        for (int j = 0; j < 8; ++j) {
            const int lj  = g * 8 + j;
            const float ang = (float)(t * BK + lj) * div;
            const float pev = (tid & 1) ? hw_cos(ang) : hw_sin(ang);
            v[j] = (_Float16)(emb[sByte[lj] * EDIM + tid] + pev);
        }
        *(f16x8*)&chunk[tile_off(tid, g)] = v;
    }
}

// ----------------------------- MFMA field kernel ----------------------------
// Champion (R14): block tile 128p x 128e (E split over 2 blocks).
// 512 thr (8 waves, 2x4), wave tile 64p x 32e, acc 4x2 f32x4 = 32 VGPR.
// LDS 36 KB; launch_bounds(512,6) -> 3 blocks/CU = 24 waves/CU.
__global__ __launch_bounds__(512, 6) void field_mfma(
    const float*    __restrict__ cpos,    // (B,P)
    const float2*   __restrict__ params,  // (B,L) {c2*log2e, log2(amp)}
    const _Float16* __restrict__ baset,   // pre-swizzled BASE^T chunks
    float*          __restrict__ out) {   // (B,P,E)

    __shared__ __align__(16) _Float16 sW[2][BM * BK];    // 2 x 8 KB
    __shared__ __align__(16) _Float16 sB[2][128 * BK];   // 2 x 8 KB (E half)
    __shared__ __align__(16) float2   sPrm[LSEQ];        // 4 KB

    const int orig = blockIdx.x;
    const int wg   = (orig & 7) * 256 + (orig >> 3);     // bijective XCD swizzle
    const int b    = wg >> 5;
    const int pt   = (wg >> 1) & 15;
    const int et   = wg & 1;

    const int tid = threadIdx.x, lane = tid & 63, wave = tid >> 6;
    const int c15 = lane & 15, g4 = lane >> 4;
    const int wrow = wave >> 2, wcol = wave & 3;         // 2 x 4 wave grid

    // W-gen role: thread -> (p row sp, k-group sg of 8 l's)
    const int sp = tid >> 2;
    const int sg = tid & 3;
    const float mypos = cpos[b * PDIM + pt * BM + sp];
    const float invL  = 1.0f / (float)(LSEQ - 1);
    const int   woff  = tile_off(sp, sg);

    // frag read offsets: A rows wrow*64 + rt*16 + c15; B rows wcol*32 + ct*16 + c15
    int aoff4[4], boff2[2];
#pragma unroll
    for (int rt = 0; rt < 4; ++rt) aoff4[rt] = tile_off(wrow * 64 + rt * 16 + c15, g4);
#pragma unroll
    for (int ct = 0; ct < 2; ++ct) boff2[ct] = tile_off(wcol * 32 + ct * 16 + c15, g4);

    // ---- prologue: sPrm -> LDS; issue B0,B1 stage (1 load/thread/buffer) ----
    sPrm[tid] = params[b * LSEQ + tid];
    // chunk = 8192 elements per (b,t); et half = 4096 elements, contiguous
    const _Float16* bt = baset + ((size_t)b * NT << 13) + et * 4096;
#pragma unroll
    for (int buf = 0; buf < 2; ++buf) {
        const _Float16* src = bt + buf * 8192 + wave * 512 + lane * 8;
        g2lds16(src, &sB[buf][wave * 512]);
    }
    __syncthreads();   // sPrm visible (staging drains too; acceptable once)

    // genW for K-step t into sW[dbuf]
    auto genW = [&](int t, int dbuf) {
        const float4* qp = (const float4*)&sPrm[t * BK + sg * 8];
        const float4 q0 = qp[0], q1 = qp[1], q2 = qp[2], q3 = qp[3];
        const float bl0 = (float)(t * BK + sg * 8) * invL;
        const float pd  = mypos - bl0;
        float w[8];
#define GW(i, c2, la) { float d = pd - (float)(i) * invL; \
                        w[i] = EXP2F(fmaf(d * d, (c2), (la))); }
        GW(0, q0.x, q0.y) GW(1, q0.z, q0.w)
        GW(2, q1.x, q1.y) GW(3, q1.z, q1.w)
        GW(4, q2.x, q2.y) GW(5, q2.z, q2.w)
        GW(6, q3.x, q3.y) GW(7, q3.z, q3.w)
#undef GW
        f16x8 wv;
        ((f16x2*)&wv)[0] = pk2(w[0], w[1]);
        ((f16x2*)&wv)[1] = pk2(w[2], w[3]);
        ((f16x2*)&wv)[2] = pk2(w[4], w[5]);
        ((f16x2*)&wv)[3] = pk2(w[6], w[7]);
        *(f16x8*)&sW[dbuf][woff] = wv;
    };

    genW(0, 0);
    __syncthreads();

    f32x4 acc[4][2];
#pragma unroll
    for (int i = 0; i < 4; ++i)
#pragma unroll
        for (int j = 0; j < 2; ++j) acc[i][j] = (f32x4)(0.f);

    // ---- main loop: one barrier per K-step (R6 ordering) ----
    for (int t = 0; t < NT; ++t) {
        const int cur = t & 1;
        if (t < NT - 1) genW(t + 1, cur ^ 1);   // spare buffer, no hazard

        const _Float16* wb = sW[cur];
        const _Float16* bb = sB[cur];
        f16x8 af[4];
#pragma unroll
        for (int rt = 0; rt < 4; ++rt) af[rt] = *(const f16x8*)&wb[aoff4[rt]];
        __builtin_amdgcn_s_setprio(1);
#pragma unroll
        for (int ct = 0; ct < 2; ++ct) {
            const f16x8 bf = *(const f16x8*)&bb[boff2[ct]];
#pragma unroll
            for (int rt = 0; rt < 4; ++rt)
                acc[rt][ct] = __builtin_amdgcn_mfma_f32_16x16x32_f16(af[rt], bf, acc[rt][ct], 0, 0, 0);
        }
        __builtin_amdgcn_s_setprio(0);

        __syncthreads();   // drains W[t+1] ds_writes + B[t+1] stage gloads

        if (t < NT - 2) {  // issue B[t+2] into the buffer just freed
            const _Float16* src = bt + (t + 2) * 8192 + wave * 512 + lane * 8;
            g2lds16(src, &sB[cur][wave * 512]);
        }
    }

    // ---- epilogue: C/D 16x16 layout col=lane&15 (e), row=g4*4+reg (p) ----
#pragma unroll
    for (int rt = 0; rt < 4; ++rt)
#pragma unroll
        for (int ct = 0; ct < 2; ++ct) {
            const int e = et * 128 + wcol * 32 + ct * 16 + c15;
#pragma unroll
            for (int reg = 0; reg < 4; ++reg) {
                const int p = pt * BM + wrow * 64 + rt * 16 + g4 * 4 + reg;
                out[((size_t)b * PDIM + p) * EDIM + e] = acc[rt][ct][reg];
            }
        }
}

extern "C" void kernel_launch(void* const* d_in, const int* in_sizes, int n_in,
                              void* d_out, int out_size, void* d_ws, size_t ws_size,
                              hipStream_t stream) {
    const int*   bs   = (const int*)d_in[0];
    const float* cpos = (const float*)d_in[1];
    const float* emb  = (const float*)d_in[2];
    const float* ls   = (const float*)d_in[3];

    const int B = in_sizes[0] / LSEQ;   // 64

    char* ws = (char*)d_ws;
    float2*   params = (float2*)ws;                   // 256 KB
    _Float16* baset  = (_Float16*)(ws + (1u << 18));  // 16 MB

    precompute_all<<<B * NT, 256, 0, stream>>>(bs, ls, emb, params, baset);
    const int nblocks = B * (PDIM / BM) * 2;          // 2048
    field_mfma<<<nblocks, 512, 0, stream>>>(cpos, params, baset, (float*)d_out);
}